// Round 2
// baseline (268.612 us; speedup 1.0000x reference)
//
#include <hip/hip_runtime.h>
#include <stdint.h>

#define N_NODES   50000
#define N_EDGES   800000
#define IN_DIM    128
#define OUT_DIM   128
#define NUM_RELS  8
#define THREADS   256

typedef _Float16 half_t;
typedef _Float16 half2v __attribute__((ext_vector_type(2)));
typedef _Float16 half4v __attribute__((ext_vector_type(4)));
typedef _Float16 half8 __attribute__((ext_vector_type(8)));
typedef float floatx4 __attribute__((ext_vector_type(4)));

// ============ plan ============
// 1. prep: WT transpose + dst histogram
// 2. scans -> off/cursors
// 3. SPLIT (round-2): scatter_kernel (no LDS, latency-bound, high occ)
//    then gemm_kernel (pure, 5 blocks/CU LDS-capped, no idle LDS holders)
//    -- round-1 counters showed fused occupancy 18% (scatter/empty slots
//       held 32KB Ws they never used, throttling gemm residency)
// 4. gather: quarter-wave (16 lanes x half8 per edge), 8 edges in flight/wave

#define NBINS3    N_NODES                         // 50000
#define NB3       ((NBINS3 + 1023) / 1024)        // 49

// ws layout (bytes) -- round-5/7 proven budget (unchanged)
#define WS_Y2     0                               // y2   : 50000 x 1024 f16 (102,400,000)
#define WS_OFF    102400000                       // off  : 50001 i32 (pad to 200,064)
#define WS_WT     102600064                       // WT   : 1024 x 128 f16 (262,144)
#define WS_BASE   102862208                       // base : N_EDGES i32 (3,200,000)
#define WS_WGT    106062208                       // wgt  : N_EDGES f16 (1,600,000)
#define WS_HIST   107662208                       // hist/cursors : 50000 i32 (200,000)
#define WS_BSUM   107862208                       // bsum : 49 i32
#define WS_NEED   (size_t)107862464

// ---- fused: WT transpose-convert + dst histogram (4 edges/thread for MLP)
#define HIST_BLOCKS ((N_EDGES + 1023) / 1024)     // 782
__global__ void prep_hist_kernel(const float* __restrict__ rel_emb, half_t* __restrict__ WT,
                                 const int* __restrict__ dst, int* __restrict__ hist) {
    int b = blockIdx.x;
    if (b < 512) {                                 // 512*256 = 131072 = 8*128*128 exactly
        int t = b * 256 + threadIdx.x;
        int r = t >> 14, k = (t >> 7) & 127, n = t & 127;
        WT[(size_t)((r << 7) | n) * 128 + k] = (half_t)rel_emb[t];
    } else {
        int i0 = (b - 512) * 1024 + threadIdx.x;
        int d[4];
        #pragma unroll
        for (int j = 0; j < 4; j++) {
            int i = i0 + j * 256;
            d[j] = (i < N_EDGES) ? dst[i] : -1;
        }
        #pragma unroll
        for (int j = 0; j < 4; j++)
            if (d[j] >= 0) atomicAdd(&hist[d[j]], 1);
    }
}

__global__ void scan1_kernel(const int* __restrict__ hist, int* __restrict__ bsum) {
    __shared__ int sh[256];
    int b = blockIdx.x, t = threadIdx.x;
    int i0 = b * 1024 + t * 4;
    int s = 0;
    #pragma unroll
    for (int j = 0; j < 4; j++) { int idx = i0 + j; if (idx < NBINS3) s += hist[idx]; }
    sh[t] = s; __syncthreads();
    for (int o = 128; o > 0; o >>= 1) { if (t < o) sh[t] += sh[t + o]; __syncthreads(); }
    if (t == 0) bsum[b] = sh[0];
}

__global__ void scan2_kernel(int* __restrict__ bsum, int* __restrict__ off) {
    __shared__ int sh[64];
    int t = threadIdx.x;
    int v = (t < NB3) ? bsum[t] : 0;
    sh[t] = v; __syncthreads();
    for (int o = 1; o < 64; o <<= 1) {
        int x = (t >= o) ? sh[t - o] : 0;
        __syncthreads();
        sh[t] += x;
        __syncthreads();
    }
    if (t < NB3) bsum[t] = sh[t] - v;
    if (t == 0) off[NBINS3] = N_EDGES;
}

__global__ void scan3_kernel(const int* __restrict__ hist, const int* __restrict__ boff,
                             int* __restrict__ off, int* __restrict__ cursors) {
    __shared__ int sh[256];
    int b = blockIdx.x, t = threadIdx.x;
    int i0 = b * 1024 + t * 4;
    int v[4]; int s = 0;
    #pragma unroll
    for (int j = 0; j < 4; j++) { int idx = i0 + j; v[j] = (idx < NBINS3) ? hist[idx] : 0; s += v[j]; }
    sh[t] = s; __syncthreads();
    for (int o = 1; o < 256; o <<= 1) {
        int x = (t >= o) ? sh[t - o] : 0;
        __syncthreads();
        sh[t] += x;
        __syncthreads();
    }
    int run = sh[t] - s + boff[b];
    #pragma unroll
    for (int j = 0; j < 4; j++) {
        int idx = i0 + j;
        if (idx < NBINS3) { off[idx] = run; cursors[idx] = run; }
        run += v[j];
    }
}

// ---- GEMM body: y2[50000 x 1024] = f16(feat) @ WT^T  (round-7 proven, unchanged)
template<bool GUARD>
__device__ __forceinline__ void gemm_body(const float* __restrict__ feat,
                                          half_t* __restrict__ Ws,   // LDS
                                          half_t* __restrict__ y2,
                                          int m0, int n0, int wave, int lane) {
    const int q = lane >> 4, l16 = lane & 15;
    const int wm0 = m0 + wave * 32;

    // hoist all feat loads (in flight during stage + barrier)
    float4 fr[2][4][2];
    #pragma unroll
    for (int ms = 0; ms < 2; ms++) {
        int node = wm0 + ms * 16 + l16;
        const float* fb = feat + (size_t)node * 128 + q * 8;
        bool ok = !GUARD || node < N_NODES;
        #pragma unroll
        for (int kk = 0; kk < 4; kk++)
            #pragma unroll
            for (int h = 0; h < 2; h++) {
                float4 v = {0.f, 0.f, 0.f, 0.f};
                if (ok) v = *(const float4*)(fb + kk * 32 + h * 4);
                fr[ms][kk][h] = v;
            }
    }
    __syncthreads();   // Ws staged

    half8 bf[2][4];
    #pragma unroll
    for (int ms = 0; ms < 2; ms++)
        #pragma unroll
        for (int kk = 0; kk < 4; kk++) {
            half8 hb;
            hb[0] = (half_t)fr[ms][kk][0].x; hb[1] = (half_t)fr[ms][kk][0].y;
            hb[2] = (half_t)fr[ms][kk][0].z; hb[3] = (half_t)fr[ms][kk][0].w;
            hb[4] = (half_t)fr[ms][kk][1].x; hb[5] = (half_t)fr[ms][kk][1].y;
            hb[6] = (half_t)fr[ms][kk][1].z; hb[7] = (half_t)fr[ms][kk][1].w;
            bf[ms][kk] = hb;
        }

    floatx4 acc[8][2];
    #pragma unroll
    for (int nt = 0; nt < 8; nt++)
        #pragma unroll
        for (int ms = 0; ms < 2; ms++) acc[nt][ms] = (floatx4){0.f, 0.f, 0.f, 0.f};

    #pragma unroll
    for (int kk = 0; kk < 4; kk++) {
        #pragma unroll
        for (int nt = 0; nt < 8; nt++) {
            int row = nt * 16 + l16;
            int phys = (kk * 4 + q) ^ (l16 & 7);
            half8 a = *(const half8*)(Ws + row * 128 + phys * 8);
            acc[nt][0] = __builtin_amdgcn_mfma_f32_16x16x32_f16(a, bf[0][kk], acc[nt][0], 0, 0, 0);
            acc[nt][1] = __builtin_amdgcn_mfma_f32_16x16x32_f16(a, bf[1][kk], acc[nt][1], 0, 0, 0);
        }
    }

    // epilogue: transpose through Ws, coalesced uint4 stores
    __syncthreads();
    #pragma unroll
    for (int nt = 0; nt < 8; nt++)
        #pragma unroll
        for (int ms = 0; ms < 2; ms++) {
            int nl = wave * 32 + ms * 16 + l16;
            int c  = nt * 4 + q;
            int p  = (c + nl) & 31;
            half4v hv;
            hv[0] = (half_t)acc[nt][ms][0]; hv[1] = (half_t)acc[nt][ms][1];
            hv[2] = (half_t)acc[nt][ms][2]; hv[3] = (half_t)acc[nt][ms][3];
            *(half4v*)(Ws + nl * 128 + p * 4) = hv;
        }
    #pragma unroll
    for (int i = 0; i < 8; i++) {
        int nl  = wave * 32 + i * 4 + (lane >> 4);
        int c16 = lane & 15;
        int p0 = (2 * c16 + nl) & 31;
        int p1 = (2 * c16 + 1 + nl) & 31;
        uint2 lo = *(const uint2*)(Ws + nl * 128 + p0 * 4);
        uint2 hi = *(const uint2*)(Ws + nl * 128 + p1 * 4);
        int node = m0 + nl;
        if (!GUARD || node < N_NODES) {
            uint4 v; v.x = lo.x; v.y = lo.y; v.z = hi.x; v.w = hi.y;
            *(uint4*)(y2 + (size_t)node * 1024 + n0 + c16 * 8) = v;
        }
    }
}

// ---- pure GEMM kernel: 3128 blocks, XCD-contiguous m-chunks (XCD = bid&7 under RR)
#define GEMM_BLOCKS 3128   // 391 m-tiles x 8 n-tiles
__global__ __launch_bounds__(THREADS) void gemm_kernel(
    const float* __restrict__ feat, const half_t* __restrict__ WT,
    half_t* __restrict__ y2) {
    __shared__ half_t Ws[128 * 128];               // 32 KB -> 5 blocks/CU
    const int bid = blockIdx.x;
    const int t = threadIdx.x;

    int work = (bid & 7) * 391 + (bid >> 3);       // 0..3127, XCD-chunked
    int mt = work >> 3, nt8 = work & 7;
    const int m0 = mt * 128, n0 = nt8 * 128;
    const int wave = t >> 6, lane = t & 63;

    for (int i = t; i < 2048; i += THREADS) {
        int row = i >> 4, lc = i & 15;
        int phys = lc ^ (row & 7);
        *(uint4*)&Ws[row * 128 + phys * 8] =
            *(const uint4*)(WT + (size_t)(n0 + row) * 128 + lc * 8);
    }
    if (m0 + 128 <= N_NODES)
        gemm_body<false>(feat, Ws, y2, m0, n0, wave, lane);
    else
        gemm_body<true>(feat, Ws, y2, m0, n0, wave, lane);
}

// ---- pure scatter kernel: no LDS, 4 edges/thread, high occupancy
__global__ __launch_bounds__(THREADS) void scatter_kernel(
    const int* __restrict__ dst, const int* __restrict__ src,
    const int* __restrict__ rel, const float* __restrict__ ew,
    int* __restrict__ cursors, int* __restrict__ base, half_t* __restrict__ wgt) {
    const int t = threadIdx.x;
    int i0 = blockIdx.x * 1024 + t;
    int d[4], s[4], r[4]; float w[4];
    #pragma unroll
    for (int j = 0; j < 4; j++) {
        int i = i0 + j * 256;
        d[j] = (i < N_EDGES) ? dst[i] : -1;
        s[j] = 0; r[j] = 0; w[j] = 0.f;
        if (d[j] >= 0) { s[j] = src[i]; r[j] = rel[i]; w[j] = ew[i]; }
    }
    #pragma unroll
    for (int j = 0; j < 4; j++) {
        if (d[j] >= 0) {
            int pos = atomicAdd(&cursors[d[j]], 1);
            base[pos] = s[j] * 1024 + r[j] * 128;
            wgt[pos] = (half_t)w[j];
        }
    }
}

// ---- gather: wave per dst, quarter-wave per edge (16 lanes x half8 = 256B/edge),
// 4 edges concurrently per wave, x2 unroll -> 8 edges in flight; shfl reduce.
__global__ __launch_bounds__(THREADS) void gather_kernel(
    const half_t* __restrict__ y2, const int* __restrict__ base,
    const half_t* __restrict__ wgt, const int* __restrict__ off,
    float* __restrict__ out) {
    int g = blockIdx.x * 4 + (threadIdx.x >> 6);
    int lane = threadIdx.x & 63;
    int q = lane >> 4, l16 = lane & 15;
    int beg = off[g], end = off[g + 1];
    const half_t* yb = y2 + l16 * 8;
    float a0[8], a1[8];
    #pragma unroll
    for (int j = 0; j < 8; j++) { a0[j] = 0.f; a1[j] = 0.f; }
    int e = beg;
    for (; e + 8 <= end; e += 8) {
        int e0 = e + q, e1 = e + 4 + q;
        int b0 = base[e0], b1 = base[e1];
        float w0 = (float)wgt[e0], w1 = (float)wgt[e1];
        half8 v0 = *(const half8*)(yb + b0);
        half8 v1 = *(const half8*)(yb + b1);
        #pragma unroll
        for (int j = 0; j < 8; j++) a0[j] += w0 * (float)v0[j];
        #pragma unroll
        for (int j = 0; j < 8; j++) a1[j] += w1 * (float)v1[j];
    }
    for (; e < end; e += 4) {
        int ee = e + q;
        int b0 = 0; float w0 = 0.f;
        if (ee < end) { b0 = base[ee]; w0 = (float)wgt[ee]; }
        half8 v0 = *(const half8*)(yb + b0);
        #pragma unroll
        for (int j = 0; j < 8; j++) a0[j] += w0 * (float)v0[j];
    }
    #pragma unroll
    for (int j = 0; j < 8; j++) {
        float s = a0[j] + a1[j];
        s += __shfl_xor(s, 16);
        s += __shfl_xor(s, 32);
        a0[j] = s;
    }
    if (q == 0) {
        float4 o0, o1;
        o0.x = a0[0]; o0.y = a0[1]; o0.z = a0[2]; o0.w = a0[3];
        o1.x = a0[4]; o1.y = a0[5]; o1.z = a0[6]; o1.w = a0[7];
        float* ob = out + (size_t)g * 128 + l16 * 8;
        *(float4*)ob = o0;
        *(float4*)(ob + 4) = o1;
    }
}

// ---- fallback (tiny ws): wave-per-edge direct with atomics
__global__ void naive_kernel(const float* __restrict__ feat, const float* __restrict__ rel_emb,
                             const float* __restrict__ ew, const int* __restrict__ src,
                             const int* __restrict__ dst, const int* __restrict__ rel,
                             float* __restrict__ out) {
    int wave = (blockIdx.x * blockDim.x + threadIdx.x) >> 6;
    int lane = threadIdx.x & 63;
    if (wave >= N_EDGES) return;
    const float* f = feat + (size_t)src[wave] * IN_DIM;
    const float* W = rel_emb + (size_t)rel[wave] * IN_DIM * OUT_DIM;
    float w = ew[wave];
    float a0 = 0.f, a1 = 0.f;
    for (int k = 0; k < IN_DIM; k++) {
        float fv = f[k];
        a0 += fv * W[k * OUT_DIM + lane];
        a1 += fv * W[k * OUT_DIM + 64 + lane];
    }
    int d = dst[wave];
    atomicAdd(&out[(size_t)d * OUT_DIM + lane], a0 * w);
    atomicAdd(&out[(size_t)d * OUT_DIM + 64 + lane], a1 * w);
}

extern "C" void kernel_launch(void* const* d_in, const int* in_sizes, int n_in,
                              void* d_out, int out_size, void* d_ws, size_t ws_size,
                              hipStream_t stream) {
    const float* feat    = (const float*)d_in[0];
    const float* rel_emb = (const float*)d_in[1];
    const float* ew      = (const float*)d_in[2];
    const int*   src     = (const int*)d_in[3];
    const int*   dst     = (const int*)d_in[4];
    const int*   rel     = (const int*)d_in[5];
    float* out = (float*)d_out;

    if (ws_size >= WS_NEED) {
        char* ws = (char*)d_ws;
        half_t* y2    = (half_t*)(ws + WS_Y2);
        int*    off   = (int*)(ws + WS_OFF);
        half_t* WT    = (half_t*)(ws + WS_WT);
        int*    basep = (int*)(ws + WS_BASE);
        half_t* wgt   = (half_t*)(ws + WS_WGT);
        int*    hist  = (int*)(ws + WS_HIST);
        int*    bsum  = (int*)(ws + WS_BSUM);

        hipMemsetAsync(hist, 0, (size_t)NBINS3 * 4, stream);
        prep_hist_kernel<<<512 + HIST_BLOCKS, THREADS, 0, stream>>>(rel_emb, WT, dst, hist);
        scan1_kernel<<<NB3, 256, 0, stream>>>(hist, bsum);
        scan2_kernel<<<1, 64, 0, stream>>>(bsum, off);
        scan3_kernel<<<NB3, 256, 0, stream>>>(hist, bsum, off, hist);  // in-place -> cursors
        scatter_kernel<<<HIST_BLOCKS, THREADS, 0, stream>>>(dst, src, rel, ew,
                                                            hist, basep, wgt);
        gemm_kernel<<<GEMM_BLOCKS, THREADS, 0, stream>>>(feat, WT, y2);
        gather_kernel<<<N_NODES / 4, THREADS, 0, stream>>>(y2, basep, wgt, off, out);
    } else {
        hipMemsetAsync(d_out, 0, (size_t)out_size * sizeof(float), stream);
        const long long total = (long long)N_EDGES * 64;
        const int blocks = (int)((total + THREADS - 1) / THREADS);
        naive_kernel<<<blocks, THREADS, 0, stream>>>(feat, rel_emb, ew, src, dst, rel, out);
    }
}

// Round 3
// 264.565 us; speedup vs baseline: 1.0153x; 1.0153x over previous
//
#include <hip/hip_runtime.h>
#include <stdint.h>

#define N_NODES   50000
#define N_EDGES   800000
#define IN_DIM    128
#define OUT_DIM   128
#define NUM_RELS  8
#define THREADS   256

typedef _Float16 half_t;
typedef _Float16 half2v __attribute__((ext_vector_type(2)));
typedef _Float16 half4v __attribute__((ext_vector_type(4)));
typedef _Float16 half8 __attribute__((ext_vector_type(8)));
typedef float floatx4 __attribute__((ext_vector_type(4)));

// ============ plan ============
// 1. prep: WT transpose + dst histogram
// 2. scans -> off/cursors
// 3. scatter: PACKED 8B record {base:int, w:f32} -> ONE random line/edge
//    (round-2 counters: WRITE_SIZE 88.8MB for 4.8MB payload; two separate
//     random 4B+2B streams each dirtied a 64B line -> 18x amplification)
// 4. gemm (pure, 5 blocks/CU)
// 5. gather: quarter-wave, reads packed records
// Fallback tiers: packed layout -> round-2 split layout -> naive.

#define NBINS3    N_NODES                         // 50000
#define NB3       ((NBINS3 + 1023) / 1024)        // 49

// ---- packed ws layout (bytes)
#define WS_Y2     0                               // y2   : 50000 x 1024 f16 (102,400,000)
#define WS_OFF    102400000                       // off  : 50001 i32 (pad to 200,064)
#define WS_WT     102600064                       // WT   : 1024 x 128 f16 (262,144)
#define WS_REC    102862208                       // rec  : N_EDGES uint2 (6,400,000)
#define WS_HIST2  109262208                       // hist/cursors : 50000 i32 (200,000)
#define WS_BSUM2  109462208                       // bsum : 49 i32 (pad 256)
#define WS_NEED2  (size_t)109462464

// ---- round-2 (unpacked) ws layout, fallback tier
#define WS_BASE   102862208                       // base : N_EDGES i32 (3,200,000)
#define WS_WGT    106062208                       // wgt  : N_EDGES f16 (1,600,000)
#define WS_HIST   107662208                       // hist/cursors : 50000 i32 (200,000)
#define WS_BSUM   107862208                       // bsum : 49 i32
#define WS_NEED   (size_t)107862464

// ---- fused: WT transpose-convert + dst histogram (4 edges/thread for MLP)
#define HIST_BLOCKS ((N_EDGES + 1023) / 1024)     // 782
__global__ void prep_hist_kernel(const float* __restrict__ rel_emb, half_t* __restrict__ WT,
                                 const int* __restrict__ dst, int* __restrict__ hist) {
    int b = blockIdx.x;
    if (b < 512) {                                 // 512*256 = 131072 = 8*128*128 exactly
        int t = b * 256 + threadIdx.x;
        int r = t >> 14, k = (t >> 7) & 127, n = t & 127;
        WT[(size_t)((r << 7) | n) * 128 + k] = (half_t)rel_emb[t];
    } else {
        int i0 = (b - 512) * 1024 + threadIdx.x;
        int d[4];
        #pragma unroll
        for (int j = 0; j < 4; j++) {
            int i = i0 + j * 256;
            d[j] = (i < N_EDGES) ? dst[i] : -1;
        }
        #pragma unroll
        for (int j = 0; j < 4; j++)
            if (d[j] >= 0) atomicAdd(&hist[d[j]], 1);
    }
}

__global__ void scan1_kernel(const int* __restrict__ hist, int* __restrict__ bsum) {
    __shared__ int sh[256];
    int b = blockIdx.x, t = threadIdx.x;
    int i0 = b * 1024 + t * 4;
    int s = 0;
    #pragma unroll
    for (int j = 0; j < 4; j++) { int idx = i0 + j; if (idx < NBINS3) s += hist[idx]; }
    sh[t] = s; __syncthreads();
    for (int o = 128; o > 0; o >>= 1) { if (t < o) sh[t] += sh[t + o]; __syncthreads(); }
    if (t == 0) bsum[b] = sh[0];
}

__global__ void scan2_kernel(int* __restrict__ bsum, int* __restrict__ off) {
    __shared__ int sh[64];
    int t = threadIdx.x;
    int v = (t < NB3) ? bsum[t] : 0;
    sh[t] = v; __syncthreads();
    for (int o = 1; o < 64; o <<= 1) {
        int x = (t >= o) ? sh[t - o] : 0;
        __syncthreads();
        sh[t] += x;
        __syncthreads();
    }
    if (t < NB3) bsum[t] = sh[t] - v;
    if (t == 0) off[NBINS3] = N_EDGES;
}

__global__ void scan3_kernel(const int* __restrict__ hist, const int* __restrict__ boff,
                             int* __restrict__ off, int* __restrict__ cursors) {
    __shared__ int sh[256];
    int b = blockIdx.x, t = threadIdx.x;
    int i0 = b * 1024 + t * 4;
    int v[4]; int s = 0;
    #pragma unroll
    for (int j = 0; j < 4; j++) { int idx = i0 + j; v[j] = (idx < NBINS3) ? hist[idx] : 0; s += v[j]; }
    sh[t] = s; __syncthreads();
    for (int o = 1; o < 256; o <<= 1) {
        int x = (t >= o) ? sh[t - o] : 0;
        __syncthreads();
        sh[t] += x;
        __syncthreads();
    }
    int run = sh[t] - s + boff[b];
    #pragma unroll
    for (int j = 0; j < 4; j++) {
        int idx = i0 + j;
        if (idx < NBINS3) { off[idx] = run; cursors[idx] = run; }
        run += v[j];
    }
}

// ---- GEMM body: y2[50000 x 1024] = f16(feat) @ WT^T  (round-7 proven, unchanged)
template<bool GUARD>
__device__ __forceinline__ void gemm_body(const float* __restrict__ feat,
                                          half_t* __restrict__ Ws,   // LDS
                                          half_t* __restrict__ y2,
                                          int m0, int n0, int wave, int lane) {
    const int q = lane >> 4, l16 = lane & 15;
    const int wm0 = m0 + wave * 32;

    // hoist all feat loads (in flight during stage + barrier)
    float4 fr[2][4][2];
    #pragma unroll
    for (int ms = 0; ms < 2; ms++) {
        int node = wm0 + ms * 16 + l16;
        const float* fb = feat + (size_t)node * 128 + q * 8;
        bool ok = !GUARD || node < N_NODES;
        #pragma unroll
        for (int kk = 0; kk < 4; kk++)
            #pragma unroll
            for (int h = 0; h < 2; h++) {
                float4 v = {0.f, 0.f, 0.f, 0.f};
                if (ok) v = *(const float4*)(fb + kk * 32 + h * 4);
                fr[ms][kk][h] = v;
            }
    }
    __syncthreads();   // Ws staged

    half8 bf[2][4];
    #pragma unroll
    for (int ms = 0; ms < 2; ms++)
        #pragma unroll
        for (int kk = 0; kk < 4; kk++) {
            half8 hb;
            hb[0] = (half_t)fr[ms][kk][0].x; hb[1] = (half_t)fr[ms][kk][0].y;
            hb[2] = (half_t)fr[ms][kk][0].z; hb[3] = (half_t)fr[ms][kk][0].w;
            hb[4] = (half_t)fr[ms][kk][1].x; hb[5] = (half_t)fr[ms][kk][1].y;
            hb[6] = (half_t)fr[ms][kk][1].z; hb[7] = (half_t)fr[ms][kk][1].w;
            bf[ms][kk] = hb;
        }

    floatx4 acc[8][2];
    #pragma unroll
    for (int nt = 0; nt < 8; nt++)
        #pragma unroll
        for (int ms = 0; ms < 2; ms++) acc[nt][ms] = (floatx4){0.f, 0.f, 0.f, 0.f};

    #pragma unroll
    for (int kk = 0; kk < 4; kk++) {
        #pragma unroll
        for (int nt = 0; nt < 8; nt++) {
            int row = nt * 16 + l16;
            int phys = (kk * 4 + q) ^ (l16 & 7);
            half8 a = *(const half8*)(Ws + row * 128 + phys * 8);
            acc[nt][0] = __builtin_amdgcn_mfma_f32_16x16x32_f16(a, bf[0][kk], acc[nt][0], 0, 0, 0);
            acc[nt][1] = __builtin_amdgcn_mfma_f32_16x16x32_f16(a, bf[1][kk], acc[nt][1], 0, 0, 0);
        }
    }

    // epilogue: transpose through Ws, coalesced uint4 stores
    __syncthreads();
    #pragma unroll
    for (int nt = 0; nt < 8; nt++)
        #pragma unroll
        for (int ms = 0; ms < 2; ms++) {
            int nl = wave * 32 + ms * 16 + l16;
            int c  = nt * 4 + q;
            int p  = (c + nl) & 31;
            half4v hv;
            hv[0] = (half_t)acc[nt][ms][0]; hv[1] = (half_t)acc[nt][ms][1];
            hv[2] = (half_t)acc[nt][ms][2]; hv[3] = (half_t)acc[nt][ms][3];
            *(half4v*)(Ws + nl * 128 + p * 4) = hv;
        }
    #pragma unroll
    for (int i = 0; i < 8; i++) {
        int nl  = wave * 32 + i * 4 + (lane >> 4);
        int c16 = lane & 15;
        int p0 = (2 * c16 + nl) & 31;
        int p1 = (2 * c16 + 1 + nl) & 31;
        uint2 lo = *(const uint2*)(Ws + nl * 128 + p0 * 4);
        uint2 hi = *(const uint2*)(Ws + nl * 128 + p1 * 4);
        int node = m0 + nl;
        if (!GUARD || node < N_NODES) {
            uint4 v; v.x = lo.x; v.y = lo.y; v.z = hi.x; v.w = hi.y;
            *(uint4*)(y2 + (size_t)node * 1024 + n0 + c16 * 8) = v;
        }
    }
}

// ---- pure GEMM kernel: 3128 blocks, XCD-contiguous m-chunks (XCD = bid&7 under RR)
#define GEMM_BLOCKS 3128   // 391 m-tiles x 8 n-tiles
__global__ __launch_bounds__(THREADS) void gemm_kernel(
    const float* __restrict__ feat, const half_t* __restrict__ WT,
    half_t* __restrict__ y2) {
    __shared__ half_t Ws[128 * 128];               // 32 KB -> 5 blocks/CU
    const int bid = blockIdx.x;
    const int t = threadIdx.x;

    int work = (bid & 7) * 391 + (bid >> 3);       // 0..3127, XCD-chunked
    int mt = work >> 3, nt8 = work & 7;
    const int m0 = mt * 128, n0 = nt8 * 128;
    const int wave = t >> 6, lane = t & 63;

    for (int i = t; i < 2048; i += THREADS) {
        int row = i >> 4, lc = i & 15;
        int phys = lc ^ (row & 7);
        *(uint4*)&Ws[row * 128 + phys * 8] =
            *(const uint4*)(WT + (size_t)(n0 + row) * 128 + lc * 8);
    }
    if (m0 + 128 <= N_NODES)
        gemm_body<false>(feat, Ws, y2, m0, n0, wave, lane);
    else
        gemm_body<true>(feat, Ws, y2, m0, n0, wave, lane);
}

// ---- PACKED scatter: one 8B record per edge -> one random line instead of two
__global__ __launch_bounds__(THREADS) void scatter_pack_kernel(
    const int* __restrict__ dst, const int* __restrict__ src,
    const int* __restrict__ rel, const float* __restrict__ ew,
    int* __restrict__ cursors, uint2* __restrict__ rec) {
    const int t = threadIdx.x;
    int i0 = blockIdx.x * 1024 + t;
    int d[4], s[4], r[4]; float w[4];
    #pragma unroll
    for (int j = 0; j < 4; j++) {
        int i = i0 + j * 256;
        d[j] = (i < N_EDGES) ? dst[i] : -1;
        s[j] = 0; r[j] = 0; w[j] = 0.f;
        if (d[j] >= 0) { s[j] = src[i]; r[j] = rel[i]; w[j] = ew[i]; }
    }
    #pragma unroll
    for (int j = 0; j < 4; j++) {
        if (d[j] >= 0) {
            int pos = atomicAdd(&cursors[d[j]], 1);
            uint2 v;
            v.x = (unsigned)(s[j] * 1024 + r[j] * 128);
            v.y = __float_as_uint(w[j]);
            rec[pos] = v;                          // single dwordx2 store
        }
    }
}

// ---- PACKED gather: wave per dst, quarter-wave per edge (16 lanes x half8),
// 8 edges in flight per wave; one 8B record load per edge.
__global__ __launch_bounds__(THREADS) void gather_pack_kernel(
    const half_t* __restrict__ y2, const uint2* __restrict__ rec,
    const int* __restrict__ off, float* __restrict__ out) {
    int g = blockIdx.x * 4 + (threadIdx.x >> 6);
    int lane = threadIdx.x & 63;
    int q = lane >> 4, l16 = lane & 15;
    int beg = off[g], end = off[g + 1];
    const half_t* yb = y2 + l16 * 8;
    float a0[8], a1[8];
    #pragma unroll
    for (int j = 0; j < 8; j++) { a0[j] = 0.f; a1[j] = 0.f; }
    int e = beg;
    for (; e + 8 <= end; e += 8) {
        uint2 r0 = rec[e + q], r1 = rec[e + 4 + q];
        float w0 = __uint_as_float(r0.y), w1 = __uint_as_float(r1.y);
        half8 v0 = *(const half8*)(yb + r0.x);
        half8 v1 = *(const half8*)(yb + r1.x);
        #pragma unroll
        for (int j = 0; j < 8; j++) a0[j] += w0 * (float)v0[j];
        #pragma unroll
        for (int j = 0; j < 8; j++) a1[j] += w1 * (float)v1[j];
    }
    for (; e < end; e += 4) {
        int ee = e + q;
        unsigned b0 = 0; float w0 = 0.f;
        if (ee < end) { uint2 r0 = rec[ee]; b0 = r0.x; w0 = __uint_as_float(r0.y); }
        half8 v0 = *(const half8*)(yb + b0);
        #pragma unroll
        for (int j = 0; j < 8; j++) a0[j] += w0 * (float)v0[j];
    }
    #pragma unroll
    for (int j = 0; j < 8; j++) {
        float s = a0[j] + a1[j];
        s += __shfl_xor(s, 16);
        s += __shfl_xor(s, 32);
        a0[j] = s;
    }
    if (q == 0) {
        float4 o0, o1;
        o0.x = a0[0]; o0.y = a0[1]; o0.z = a0[2]; o0.w = a0[3];
        o1.x = a0[4]; o1.y = a0[5]; o1.z = a0[6]; o1.w = a0[7];
        float* ob = out + (size_t)g * 128 + l16 * 8;
        *(float4*)ob = o0;
        *(float4*)(ob + 4) = o1;
    }
}

// ---- round-2 fallback tier: unpacked scatter/gather (proven)
__global__ __launch_bounds__(THREADS) void scatter_kernel(
    const int* __restrict__ dst, const int* __restrict__ src,
    const int* __restrict__ rel, const float* __restrict__ ew,
    int* __restrict__ cursors, int* __restrict__ base, half_t* __restrict__ wgt) {
    const int t = threadIdx.x;
    int i0 = blockIdx.x * 1024 + t;
    int d[4], s[4], r[4]; float w[4];
    #pragma unroll
    for (int j = 0; j < 4; j++) {
        int i = i0 + j * 256;
        d[j] = (i < N_EDGES) ? dst[i] : -1;
        s[j] = 0; r[j] = 0; w[j] = 0.f;
        if (d[j] >= 0) { s[j] = src[i]; r[j] = rel[i]; w[j] = ew[i]; }
    }
    #pragma unroll
    for (int j = 0; j < 4; j++) {
        if (d[j] >= 0) {
            int pos = atomicAdd(&cursors[d[j]], 1);
            base[pos] = s[j] * 1024 + r[j] * 128;
            wgt[pos] = (half_t)w[j];
        }
    }
}

__global__ __launch_bounds__(THREADS) void gather_kernel(
    const half_t* __restrict__ y2, const int* __restrict__ base,
    const half_t* __restrict__ wgt, const int* __restrict__ off,
    float* __restrict__ out) {
    int g = blockIdx.x * 4 + (threadIdx.x >> 6);
    int lane = threadIdx.x & 63;
    int q = lane >> 4, l16 = lane & 15;
    int beg = off[g], end = off[g + 1];
    const half_t* yb = y2 + l16 * 8;
    float a0[8], a1[8];
    #pragma unroll
    for (int j = 0; j < 8; j++) { a0[j] = 0.f; a1[j] = 0.f; }
    int e = beg;
    for (; e + 8 <= end; e += 8) {
        int e0 = e + q, e1 = e + 4 + q;
        int b0 = base[e0], b1 = base[e1];
        float w0 = (float)wgt[e0], w1 = (float)wgt[e1];
        half8 v0 = *(const half8*)(yb + b0);
        half8 v1 = *(const half8*)(yb + b1);
        #pragma unroll
        for (int j = 0; j < 8; j++) a0[j] += w0 * (float)v0[j];
        #pragma unroll
        for (int j = 0; j < 8; j++) a1[j] += w1 * (float)v1[j];
    }
    for (; e < end; e += 4) {
        int ee = e + q;
        int b0 = 0; float w0 = 0.f;
        if (ee < end) { b0 = base[ee]; w0 = (float)wgt[ee]; }
        half8 v0 = *(const half8*)(yb + b0);
        #pragma unroll
        for (int j = 0; j < 8; j++) a0[j] += w0 * (float)v0[j];
    }
    #pragma unroll
    for (int j = 0; j < 8; j++) {
        float s = a0[j] + a1[j];
        s += __shfl_xor(s, 16);
        s += __shfl_xor(s, 32);
        a0[j] = s;
    }
    if (q == 0) {
        float4 o0, o1;
        o0.x = a0[0]; o0.y = a0[1]; o0.z = a0[2]; o0.w = a0[3];
        o1.x = a0[4]; o1.y = a0[5]; o1.z = a0[6]; o1.w = a0[7];
        float* ob = out + (size_t)g * 128 + l16 * 8;
        *(float4*)ob = o0;
        *(float4*)(ob + 4) = o1;
    }
}

// ---- fallback (tiny ws): wave-per-edge direct with atomics
__global__ void naive_kernel(const float* __restrict__ feat, const float* __restrict__ rel_emb,
                             const float* __restrict__ ew, const int* __restrict__ src,
                             const int* __restrict__ dst, const int* __restrict__ rel,
                             float* __restrict__ out) {
    int wave = (blockIdx.x * blockDim.x + threadIdx.x) >> 6;
    int lane = threadIdx.x & 63;
    if (wave >= N_EDGES) return;
    const float* f = feat + (size_t)src[wave] * IN_DIM;
    const float* W = rel_emb + (size_t)rel[wave] * IN_DIM * OUT_DIM;
    float w = ew[wave];
    float a0 = 0.f, a1 = 0.f;
    for (int k = 0; k < IN_DIM; k++) {
        float fv = f[k];
        a0 += fv * W[k * OUT_DIM + lane];
        a1 += fv * W[k * OUT_DIM + 64 + lane];
    }
    int d = dst[wave];
    atomicAdd(&out[(size_t)d * OUT_DIM + lane], a0 * w);
    atomicAdd(&out[(size_t)d * OUT_DIM + 64 + lane], a1 * w);
}

extern "C" void kernel_launch(void* const* d_in, const int* in_sizes, int n_in,
                              void* d_out, int out_size, void* d_ws, size_t ws_size,
                              hipStream_t stream) {
    const float* feat    = (const float*)d_in[0];
    const float* rel_emb = (const float*)d_in[1];
    const float* ew      = (const float*)d_in[2];
    const int*   src     = (const int*)d_in[3];
    const int*   dst     = (const int*)d_in[4];
    const int*   rel     = (const int*)d_in[5];
    float* out = (float*)d_out;

    if (ws_size >= WS_NEED2) {
        // ---- packed tier
        char* ws = (char*)d_ws;
        half_t* y2    = (half_t*)(ws + WS_Y2);
        int*    off   = (int*)(ws + WS_OFF);
        half_t* WT    = (half_t*)(ws + WS_WT);
        uint2*  rec   = (uint2*)(ws + WS_REC);
        int*    hist  = (int*)(ws + WS_HIST2);
        int*    bsum  = (int*)(ws + WS_BSUM2);

        hipMemsetAsync(hist, 0, (size_t)NBINS3 * 4, stream);
        prep_hist_kernel<<<512 + HIST_BLOCKS, THREADS, 0, stream>>>(rel_emb, WT, dst, hist);
        scan1_kernel<<<NB3, 256, 0, stream>>>(hist, bsum);
        scan2_kernel<<<1, 64, 0, stream>>>(bsum, off);
        scan3_kernel<<<NB3, 256, 0, stream>>>(hist, bsum, off, hist);  // in-place -> cursors
        scatter_pack_kernel<<<HIST_BLOCKS, THREADS, 0, stream>>>(dst, src, rel, ew, hist, rec);
        gemm_kernel<<<GEMM_BLOCKS, THREADS, 0, stream>>>(feat, WT, y2);
        gather_pack_kernel<<<N_NODES / 4, THREADS, 0, stream>>>(y2, rec, off, out);
    } else if (ws_size >= WS_NEED) {
        // ---- round-2 tier (unpacked)
        char* ws = (char*)d_ws;
        half_t* y2    = (half_t*)(ws + WS_Y2);
        int*    off   = (int*)(ws + WS_OFF);
        half_t* WT    = (half_t*)(ws + WS_WT);
        int*    basep = (int*)(ws + WS_BASE);
        half_t* wgt   = (half_t*)(ws + WS_WGT);
        int*    hist  = (int*)(ws + WS_HIST);
        int*    bsum  = (int*)(ws + WS_BSUM);

        hipMemsetAsync(hist, 0, (size_t)NBINS3 * 4, stream);
        prep_hist_kernel<<<512 + HIST_BLOCKS, THREADS, 0, stream>>>(rel_emb, WT, dst, hist);
        scan1_kernel<<<NB3, 256, 0, stream>>>(hist, bsum);
        scan2_kernel<<<1, 64, 0, stream>>>(bsum, off);
        scan3_kernel<<<NB3, 256, 0, stream>>>(hist, bsum, off, hist);
        scatter_kernel<<<HIST_BLOCKS, THREADS, 0, stream>>>(dst, src, rel, ew,
                                                            hist, basep, wgt);
        gemm_kernel<<<GEMM_BLOCKS, THREADS, 0, stream>>>(feat, WT, y2);
        gather_kernel<<<N_NODES / 4, THREADS, 0, stream>>>(y2, basep, wgt, off, out);
    } else {
        hipMemsetAsync(d_out, 0, (size_t)out_size * sizeof(float), stream);
        const long long total = (long long)N_EDGES * 64;
        const int blocks = (int)((total + THREADS - 1) / THREADS);
        naive_kernel<<<blocks, THREADS, 0, stream>>>(feat, rel_emb, ew, src, dst, rel, out);
    }
}

// Round 4
// 224.137 us; speedup vs baseline: 1.1984x; 1.1804x over previous
//
#include <hip/hip_runtime.h>
#include <stdint.h>

#define N_NODES   50000
#define N_EDGES   800000
#define IN_DIM    128
#define OUT_DIM   128
#define NUM_RELS  8
#define THREADS   256

typedef _Float16 half_t;
typedef _Float16 half2v __attribute__((ext_vector_type(2)));
typedef _Float16 half4v __attribute__((ext_vector_type(4)));
typedef _Float16 half8 __attribute__((ext_vector_type(8)));
typedef float floatx4 __attribute__((ext_vector_type(4)));

// ============ plan (round 4) ============
// 1. prep: WT transpose + dst histogram WITH rank capture
//    rank[i] = atomicAdd(&hist[dst[i]],1)  -> rank stored coalesced in d_out
//    (d_out is dead scratch until gather fully overwrites it)
// 2. scans -> off
// 3. gemm_scatter fused: gemm body + 256-edge fire-and-forget scatter tail
//    pos = off[dst] + rank  (NO atomic; round-3 showed scatter was not
//    BW-bound: WRITE halved 88.8->52.4MB, dur 70->68us -> atomic chain +
//    low concurrency was the cost; stores now hide under MFMA phases)
// 4. gather: quarter-wave, packed 8B records (proven)
// Fallback tiers: rank-packed -> round-2 split layout -> naive.

#define NBINS3    N_NODES                         // 50000
#define NB3       ((NBINS3 + 1023) / 1024)        // 49

// ---- packed ws layout (bytes) -- same as round 3 (rank lives in d_out)
#define WS_Y2     0                               // y2   : 50000 x 1024 f16 (102,400,000)
#define WS_OFF    102400000                       // off  : 50001 i32 (pad to 200,064)
#define WS_WT     102600064                       // WT   : 1024 x 128 f16 (262,144)
#define WS_REC    102862208                       // rec  : N_EDGES uint2 (6,400,000)
#define WS_HIST2  109262208                       // hist/cursors : 50000 i32 (200,000)
#define WS_BSUM2  109462208                       // bsum : 49 i32 (pad 256)
#define WS_NEED2  (size_t)109462464

// ---- round-2 (unpacked) ws layout, fallback tier
#define WS_BASE   102862208                       // base : N_EDGES i32 (3,200,000)
#define WS_WGT    106062208                       // wgt  : N_EDGES f16 (1,600,000)
#define WS_HIST   107662208                       // hist/cursors : 50000 i32 (200,000)
#define WS_BSUM   107862208                       // bsum : 49 i32
#define WS_NEED   (size_t)107862464

#define EDGE_BLOCKS ((N_EDGES + 255) / 256)       // 3125

// ---- prep with rank capture: WT transpose (512 blocks) + hist/rank (3125 blocks)
__global__ void prep_rank_kernel(const float* __restrict__ rel_emb, half_t* __restrict__ WT,
                                 const int* __restrict__ dst, int* __restrict__ hist,
                                 int* __restrict__ rank) {
    int b = blockIdx.x;
    if (b < 512) {                                 // 512*256 = 131072 = 8*128*128 exactly
        int t = b * 256 + threadIdx.x;
        int r = t >> 14, k = (t >> 7) & 127, n = t & 127;
        WT[(size_t)((r << 7) | n) * 128 + k] = (half_t)rel_emb[t];
    } else {
        int i = (b - 512) * 256 + threadIdx.x;
        if (i < N_EDGES)
            rank[i] = atomicAdd(&hist[dst[i]], 1);  // coalesced rank store
    }
}

// ---- legacy prep (fallback tier)
#define HIST_BLOCKS ((N_EDGES + 1023) / 1024)     // 782
__global__ void prep_hist_kernel(const float* __restrict__ rel_emb, half_t* __restrict__ WT,
                                 const int* __restrict__ dst, int* __restrict__ hist) {
    int b = blockIdx.x;
    if (b < 512) {
        int t = b * 256 + threadIdx.x;
        int r = t >> 14, k = (t >> 7) & 127, n = t & 127;
        WT[(size_t)((r << 7) | n) * 128 + k] = (half_t)rel_emb[t];
    } else {
        int i0 = (b - 512) * 1024 + threadIdx.x;
        int d[4];
        #pragma unroll
        for (int j = 0; j < 4; j++) {
            int i = i0 + j * 256;
            d[j] = (i < N_EDGES) ? dst[i] : -1;
        }
        #pragma unroll
        for (int j = 0; j < 4; j++)
            if (d[j] >= 0) atomicAdd(&hist[d[j]], 1);
    }
}

__global__ void scan1_kernel(const int* __restrict__ hist, int* __restrict__ bsum) {
    __shared__ int sh[256];
    int b = blockIdx.x, t = threadIdx.x;
    int i0 = b * 1024 + t * 4;
    int s = 0;
    #pragma unroll
    for (int j = 0; j < 4; j++) { int idx = i0 + j; if (idx < NBINS3) s += hist[idx]; }
    sh[t] = s; __syncthreads();
    for (int o = 128; o > 0; o >>= 1) { if (t < o) sh[t] += sh[t + o]; __syncthreads(); }
    if (t == 0) bsum[b] = sh[0];
}

__global__ void scan2_kernel(int* __restrict__ bsum, int* __restrict__ off) {
    __shared__ int sh[64];
    int t = threadIdx.x;
    int v = (t < NB3) ? bsum[t] : 0;
    sh[t] = v; __syncthreads();
    for (int o = 1; o < 64; o <<= 1) {
        int x = (t >= o) ? sh[t - o] : 0;
        __syncthreads();
        sh[t] += x;
        __syncthreads();
    }
    if (t < NB3) bsum[t] = sh[t] - v;
    if (t == 0) off[NBINS3] = N_EDGES;
}

__global__ void scan3_kernel(const int* __restrict__ hist, const int* __restrict__ boff,
                             int* __restrict__ off, int* __restrict__ cursors) {
    __shared__ int sh[256];
    int b = blockIdx.x, t = threadIdx.x;
    int i0 = b * 1024 + t * 4;
    int v[4]; int s = 0;
    #pragma unroll
    for (int j = 0; j < 4; j++) { int idx = i0 + j; v[j] = (idx < NBINS3) ? hist[idx] : 0; s += v[j]; }
    sh[t] = s; __syncthreads();
    for (int o = 1; o < 256; o <<= 1) {
        int x = (t >= o) ? sh[t - o] : 0;
        __syncthreads();
        sh[t] += x;
        __syncthreads();
    }
    int run = sh[t] - s + boff[b];
    #pragma unroll
    for (int j = 0; j < 4; j++) {
        int idx = i0 + j;
        if (idx < NBINS3) { off[idx] = run; cursors[idx] = run; }
        run += v[j];
    }
}

// ---- GEMM body: y2[50000 x 1024] = f16(feat) @ WT^T  (round-7 proven, unchanged)
template<bool GUARD>
__device__ __forceinline__ void gemm_body(const float* __restrict__ feat,
                                          half_t* __restrict__ Ws,   // LDS
                                          half_t* __restrict__ y2,
                                          int m0, int n0, int wave, int lane) {
    const int q = lane >> 4, l16 = lane & 15;
    const int wm0 = m0 + wave * 32;

    // hoist all feat loads (in flight during stage + barrier)
    float4 fr[2][4][2];
    #pragma unroll
    for (int ms = 0; ms < 2; ms++) {
        int node = wm0 + ms * 16 + l16;
        const float* fb = feat + (size_t)node * 128 + q * 8;
        bool ok = !GUARD || node < N_NODES;
        #pragma unroll
        for (int kk = 0; kk < 4; kk++)
            #pragma unroll
            for (int h = 0; h < 2; h++) {
                float4 v = {0.f, 0.f, 0.f, 0.f};
                if (ok) v = *(const float4*)(fb + kk * 32 + h * 4);
                fr[ms][kk][h] = v;
            }
    }
    __syncthreads();   // Ws staged

    half8 bf[2][4];
    #pragma unroll
    for (int ms = 0; ms < 2; ms++)
        #pragma unroll
        for (int kk = 0; kk < 4; kk++) {
            half8 hb;
            hb[0] = (half_t)fr[ms][kk][0].x; hb[1] = (half_t)fr[ms][kk][0].y;
            hb[2] = (half_t)fr[ms][kk][0].z; hb[3] = (half_t)fr[ms][kk][0].w;
            hb[4] = (half_t)fr[ms][kk][1].x; hb[5] = (half_t)fr[ms][kk][1].y;
            hb[6] = (half_t)fr[ms][kk][1].z; hb[7] = (half_t)fr[ms][kk][1].w;
            bf[ms][kk] = hb;
        }

    floatx4 acc[8][2];
    #pragma unroll
    for (int nt = 0; nt < 8; nt++)
        #pragma unroll
        for (int ms = 0; ms < 2; ms++) acc[nt][ms] = (floatx4){0.f, 0.f, 0.f, 0.f};

    #pragma unroll
    for (int kk = 0; kk < 4; kk++) {
        #pragma unroll
        for (int nt = 0; nt < 8; nt++) {
            int row = nt * 16 + l16;
            int phys = (kk * 4 + q) ^ (l16 & 7);
            half8 a = *(const half8*)(Ws + row * 128 + phys * 8);
            acc[nt][0] = __builtin_amdgcn_mfma_f32_16x16x32_f16(a, bf[0][kk], acc[nt][0], 0, 0, 0);
            acc[nt][1] = __builtin_amdgcn_mfma_f32_16x16x32_f16(a, bf[1][kk], acc[nt][1], 0, 0, 0);
        }
    }

    // epilogue: transpose through Ws, coalesced uint4 stores
    __syncthreads();
    #pragma unroll
    for (int nt = 0; nt < 8; nt++)
        #pragma unroll
        for (int ms = 0; ms < 2; ms++) {
            int nl = wave * 32 + ms * 16 + l16;
            int c  = nt * 4 + q;
            int p  = (c + nl) & 31;
            half4v hv;
            hv[0] = (half_t)acc[nt][ms][0]; hv[1] = (half_t)acc[nt][ms][1];
            hv[2] = (half_t)acc[nt][ms][2]; hv[3] = (half_t)acc[nt][ms][3];
            *(half4v*)(Ws + nl * 128 + p * 4) = hv;
        }
    #pragma unroll
    for (int i = 0; i < 8; i++) {
        int nl  = wave * 32 + i * 4 + (lane >> 4);
        int c16 = lane & 15;
        int p0 = (2 * c16 + nl) & 31;
        int p1 = (2 * c16 + 1 + nl) & 31;
        uint2 lo = *(const uint2*)(Ws + nl * 128 + p0 * 4);
        uint2 hi = *(const uint2*)(Ws + nl * 128 + p1 * 4);
        int node = m0 + nl;
        if (!GUARD || node < N_NODES) {
            uint4 v; v.x = lo.x; v.y = lo.y; v.z = hi.x; v.w = hi.y;
            *(uint4*)(y2 + (size_t)node * 1024 + n0 + c16 * 8) = v;
        }
    }
}

// ---- FUSED gemm + atomic-free scatter tail
// 3128 blocks >= 3125 edge chunks of 256. Edge loads hoisted to entry so they
// are in flight under the whole MFMA body; tail is pure fire-and-forget stores.
#define GEMM_BLOCKS 3128   // 391 m-tiles x 8 n-tiles
__global__ __launch_bounds__(THREADS) void gemm_scatter_kernel(
    const float* __restrict__ feat, const half_t* __restrict__ WT,
    half_t* __restrict__ y2,
    const int* __restrict__ dst, const int* __restrict__ src,
    const int* __restrict__ rel, const float* __restrict__ ew,
    const int* __restrict__ rank, const int* __restrict__ off,
    uint2* __restrict__ rec) {
    __shared__ half_t Ws[128 * 128];               // 32 KB -> 5 blocks/CU
    const int bid = blockIdx.x;
    const int t = threadIdx.x;

    // hoisted edge loads (coalesced; consumed only at the tail)
    int ei = bid * 256 + t;
    int ed = -1, es = 0, er = 0, rk = 0; float wv = 0.f;
    if (ei < N_EDGES) {
        ed = dst[ei]; es = src[ei]; er = rel[ei];
        wv = ew[ei];  rk = rank[ei];
    }

    int work = (bid & 7) * 391 + (bid >> 3);       // 0..3127, XCD-chunked
    int mt = work >> 3, nt8 = work & 7;
    const int m0 = mt * 128, n0 = nt8 * 128;
    const int wave = t >> 6, lane = t & 63;

    for (int i = t; i < 2048; i += THREADS) {
        int row = i >> 4, lc = i & 15;
        int phys = lc ^ (row & 7);
        *(uint4*)&Ws[row * 128 + phys * 8] =
            *(const uint4*)(WT + (size_t)(n0 + row) * 128 + lc * 8);
    }
    if (m0 + 128 <= N_NODES)
        gemm_body<false>(feat, Ws, y2, m0, n0, wave, lane);
    else
        gemm_body<true>(feat, Ws, y2, m0, n0, wave, lane);

    // scatter tail: deterministic placement, no atomic
    if (ed >= 0) {
        int pos = off[ed] + rk;
        uint2 v;
        v.x = (unsigned)(es * 1024 + er * 128);
        v.y = __float_as_uint(wv);
        rec[pos] = v;
    }
}

// ---- PACKED gather: wave per dst, quarter-wave per edge (16 lanes x half8),
// 8 edges in flight per wave; one 8B record load per edge.
__global__ __launch_bounds__(THREADS) void gather_pack_kernel(
    const half_t* __restrict__ y2, const uint2* __restrict__ rec,
    const int* __restrict__ off, float* __restrict__ out) {
    int g = blockIdx.x * 4 + (threadIdx.x >> 6);
    int lane = threadIdx.x & 63;
    int q = lane >> 4, l16 = lane & 15;
    int beg = off[g], end = off[g + 1];
    const half_t* yb = y2 + l16 * 8;
    float a0[8], a1[8];
    #pragma unroll
    for (int j = 0; j < 8; j++) { a0[j] = 0.f; a1[j] = 0.f; }
    int e = beg;
    for (; e + 8 <= end; e += 8) {
        uint2 r0 = rec[e + q], r1 = rec[e + 4 + q];
        float w0 = __uint_as_float(r0.y), w1 = __uint_as_float(r1.y);
        half8 v0 = *(const half8*)(yb + r0.x);
        half8 v1 = *(const half8*)(yb + r1.x);
        #pragma unroll
        for (int j = 0; j < 8; j++) a0[j] += w0 * (float)v0[j];
        #pragma unroll
        for (int j = 0; j < 8; j++) a1[j] += w1 * (float)v1[j];
    }
    for (; e < end; e += 4) {
        int ee = e + q;
        unsigned b0 = 0; float w0 = 0.f;
        if (ee < end) { uint2 r0 = rec[ee]; b0 = r0.x; w0 = __uint_as_float(r0.y); }
        half8 v0 = *(const half8*)(yb + b0);
        #pragma unroll
        for (int j = 0; j < 8; j++) a0[j] += w0 * (float)v0[j];
    }
    #pragma unroll
    for (int j = 0; j < 8; j++) {
        float s = a0[j] + a1[j];
        s += __shfl_xor(s, 16);
        s += __shfl_xor(s, 32);
        a0[j] = s;
    }
    if (q == 0) {
        float4 o0, o1;
        o0.x = a0[0]; o0.y = a0[1]; o0.z = a0[2]; o0.w = a0[3];
        o1.x = a0[4]; o1.y = a0[5]; o1.z = a0[6]; o1.w = a0[7];
        float* ob = out + (size_t)g * 128 + l16 * 8;
        *(float4*)ob = o0;
        *(float4*)(ob + 4) = o1;
    }
}

// ---- round-2 fallback tier: unpacked scatter/gather + plain gemm (proven)
__global__ __launch_bounds__(THREADS) void gemm_kernel(
    const float* __restrict__ feat, const half_t* __restrict__ WT,
    half_t* __restrict__ y2) {
    __shared__ half_t Ws[128 * 128];
    const int bid = blockIdx.x;
    const int t = threadIdx.x;
    int work = (bid & 7) * 391 + (bid >> 3);
    int mt = work >> 3, nt8 = work & 7;
    const int m0 = mt * 128, n0 = nt8 * 128;
    const int wave = t >> 6, lane = t & 63;
    for (int i = t; i < 2048; i += THREADS) {
        int row = i >> 4, lc = i & 15;
        int phys = lc ^ (row & 7);
        *(uint4*)&Ws[row * 128 + phys * 8] =
            *(const uint4*)(WT + (size_t)(n0 + row) * 128 + lc * 8);
    }
    if (m0 + 128 <= N_NODES)
        gemm_body<false>(feat, Ws, y2, m0, n0, wave, lane);
    else
        gemm_body<true>(feat, Ws, y2, m0, n0, wave, lane);
}

__global__ __launch_bounds__(THREADS) void scatter_kernel(
    const int* __restrict__ dst, const int* __restrict__ src,
    const int* __restrict__ rel, const float* __restrict__ ew,
    int* __restrict__ cursors, int* __restrict__ base, half_t* __restrict__ wgt) {
    const int t = threadIdx.x;
    int i0 = blockIdx.x * 1024 + t;
    int d[4], s[4], r[4]; float w[4];
    #pragma unroll
    for (int j = 0; j < 4; j++) {
        int i = i0 + j * 256;
        d[j] = (i < N_EDGES) ? dst[i] : -1;
        s[j] = 0; r[j] = 0; w[j] = 0.f;
        if (d[j] >= 0) { s[j] = src[i]; r[j] = rel[i]; w[j] = ew[i]; }
    }
    #pragma unroll
    for (int j = 0; j < 4; j++) {
        if (d[j] >= 0) {
            int pos = atomicAdd(&cursors[d[j]], 1);
            base[pos] = s[j] * 1024 + r[j] * 128;
            wgt[pos] = (half_t)w[j];
        }
    }
}

__global__ __launch_bounds__(THREADS) void gather_kernel(
    const half_t* __restrict__ y2, const int* __restrict__ base,
    const half_t* __restrict__ wgt, const int* __restrict__ off,
    float* __restrict__ out) {
    int g = blockIdx.x * 4 + (threadIdx.x >> 6);
    int lane = threadIdx.x & 63;
    int q = lane >> 4, l16 = lane & 15;
    int beg = off[g], end = off[g + 1];
    const half_t* yb = y2 + l16 * 8;
    float a0[8], a1[8];
    #pragma unroll
    for (int j = 0; j < 8; j++) { a0[j] = 0.f; a1[j] = 0.f; }
    int e = beg;
    for (; e + 8 <= end; e += 8) {
        int e0 = e + q, e1 = e + 4 + q;
        int b0 = base[e0], b1 = base[e1];
        float w0 = (float)wgt[e0], w1 = (float)wgt[e1];
        half8 v0 = *(const half8*)(yb + b0);
        half8 v1 = *(const half8*)(yb + b1);
        #pragma unroll
        for (int j = 0; j < 8; j++) a0[j] += w0 * (float)v0[j];
        #pragma unroll
        for (int j = 0; j < 8; j++) a1[j] += w1 * (float)v1[j];
    }
    for (; e < end; e += 4) {
        int ee = e + q;
        int b0 = 0; float w0 = 0.f;
        if (ee < end) { b0 = base[ee]; w0 = (float)wgt[ee]; }
        half8 v0 = *(const half8*)(yb + b0);
        #pragma unroll
        for (int j = 0; j < 8; j++) a0[j] += w0 * (float)v0[j];
    }
    #pragma unroll
    for (int j = 0; j < 8; j++) {
        float s = a0[j] + a1[j];
        s += __shfl_xor(s, 16);
        s += __shfl_xor(s, 32);
        a0[j] = s;
    }
    if (q == 0) {
        float4 o0, o1;
        o0.x = a0[0]; o0.y = a0[1]; o0.z = a0[2]; o0.w = a0[3];
        o1.x = a0[4]; o1.y = a0[5]; o1.z = a0[6]; o1.w = a0[7];
        float* ob = out + (size_t)g * 128 + l16 * 8;
        *(float4*)ob = o0;
        *(float4*)(ob + 4) = o1;
    }
}

// ---- fallback (tiny ws): wave-per-edge direct with atomics
__global__ void naive_kernel(const float* __restrict__ feat, const float* __restrict__ rel_emb,
                             const float* __restrict__ ew, const int* __restrict__ src,
                             const int* __restrict__ dst, const int* __restrict__ rel,
                             float* __restrict__ out) {
    int wave = (blockIdx.x * blockDim.x + threadIdx.x) >> 6;
    int lane = threadIdx.x & 63;
    if (wave >= N_EDGES) return;
    const float* f = feat + (size_t)src[wave] * IN_DIM;
    const float* W = rel_emb + (size_t)rel[wave] * IN_DIM * OUT_DIM;
    float w = ew[wave];
    float a0 = 0.f, a1 = 0.f;
    for (int k = 0; k < IN_DIM; k++) {
        float fv = f[k];
        a0 += fv * W[k * OUT_DIM + lane];
        a1 += fv * W[k * OUT_DIM + 64 + lane];
    }
    int d = dst[wave];
    atomicAdd(&out[(size_t)d * OUT_DIM + lane], a0 * w);
    atomicAdd(&out[(size_t)d * OUT_DIM + 64 + lane], a1 * w);
}

extern "C" void kernel_launch(void* const* d_in, const int* in_sizes, int n_in,
                              void* d_out, int out_size, void* d_ws, size_t ws_size,
                              hipStream_t stream) {
    const float* feat    = (const float*)d_in[0];
    const float* rel_emb = (const float*)d_in[1];
    const float* ew      = (const float*)d_in[2];
    const int*   src     = (const int*)d_in[3];
    const int*   dst     = (const int*)d_in[4];
    const int*   rel     = (const int*)d_in[5];
    float* out = (float*)d_out;

    if (ws_size >= WS_NEED2) {
        // ---- rank-packed tier
        char* ws = (char*)d_ws;
        half_t* y2    = (half_t*)(ws + WS_Y2);
        int*    off   = (int*)(ws + WS_OFF);
        half_t* WT    = (half_t*)(ws + WS_WT);
        uint2*  rec   = (uint2*)(ws + WS_REC);
        int*    hist  = (int*)(ws + WS_HIST2);
        int*    bsum  = (int*)(ws + WS_BSUM2);
        int*    rank  = (int*)d_out;   // dead scratch until gather overwrites out

        hipMemsetAsync(hist, 0, (size_t)NBINS3 * 4, stream);
        prep_rank_kernel<<<512 + EDGE_BLOCKS, THREADS, 0, stream>>>(rel_emb, WT, dst, hist, rank);
        scan1_kernel<<<NB3, 256, 0, stream>>>(hist, bsum);
        scan2_kernel<<<1, 64, 0, stream>>>(bsum, off);
        scan3_kernel<<<NB3, 256, 0, stream>>>(hist, bsum, off, hist);  // in-place -> (unused) cursors
        gemm_scatter_kernel<<<GEMM_BLOCKS, THREADS, 0, stream>>>(feat, WT, y2, dst, src, rel,
                                                                 ew, rank, off, rec);
        gather_pack_kernel<<<N_NODES / 4, THREADS, 0, stream>>>(y2, rec, off, out);
    } else if (ws_size >= WS_NEED) {
        // ---- round-2 tier (unpacked)
        char* ws = (char*)d_ws;
        half_t* y2    = (half_t*)(ws + WS_Y2);
        int*    off   = (int*)(ws + WS_OFF);
        half_t* WT    = (half_t*)(ws + WS_WT);
        int*    basep = (int*)(ws + WS_BASE);
        half_t* wgt   = (half_t*)(ws + WS_WGT);
        int*    hist  = (int*)(ws + WS_HIST);
        int*    bsum  = (int*)(ws + WS_BSUM);

        hipMemsetAsync(hist, 0, (size_t)NBINS3 * 4, stream);
        prep_hist_kernel<<<512 + HIST_BLOCKS, THREADS, 0, stream>>>(rel_emb, WT, dst, hist);
        scan1_kernel<<<NB3, 256, 0, stream>>>(hist, bsum);
        scan2_kernel<<<1, 64, 0, stream>>>(bsum, off);
        scan3_kernel<<<NB3, 256, 0, stream>>>(hist, bsum, off, hist);
        scatter_kernel<<<HIST_BLOCKS, THREADS, 0, stream>>>(dst, src, rel, ew,
                                                            hist, basep, wgt);
        gemm_kernel<<<GEMM_BLOCKS, THREADS, 0, stream>>>(feat, WT, y2);
        gather_kernel<<<N_NODES / 4, THREADS, 0, stream>>>(y2, basep, wgt, off, out);
    } else {
        hipMemsetAsync(d_out, 0, (size_t)out_size * sizeof(float), stream);
        const long long total = (long long)N_EDGES * 64;
        const int blocks = (int)((total + THREADS - 1) / THREADS);
        naive_kernel<<<blocks, THREADS, 0, stream>>>(feat, rel_emb, ew, src, dst, rel, out);
    }
}